// Round 12
// baseline (1926.025 us; speedup 1.0000x reference)
//
#include <hip/hip_runtime.h>
#include <math.h>

typedef __bf16 bf16x8 __attribute__((ext_vector_type(8)));
typedef float f32x4 __attribute__((ext_vector_type(4)));
typedef unsigned int u32x4 __attribute__((ext_vector_type(4)));
typedef unsigned long long u64;

constexpr int QQ = 1027;   // states
constexpr int SS = 26;     // alphabet
constexpr int TT = 512;    // sequence length
constexpr int NB = 256;    // batch
constexpr int KP = 1056;   // K padded in LDS (33 ksteps of 32)
constexpr int NP = 1040;   // N padded (65 tiles of 16) = exchanged row length
constexpr int BTS = 1040;  // Bt row stride (floats)
constexpr int NSL = 13;    // N slices (5 tiles = 80 cols each)
constexpr int NBB = 16;    // batch blocks
constexpr int MB = 16;     // batch rows per block
constexpr int NWV = 5;     // waves per WG (1 col-tile each)
constexpr int CBLK = NWV * 64;       // 320
constexpr int KSTEPS = KP / 32;      // 33
constexpr int BUFN = NB * NP;        // bf16 elems per alpha slot (no pads!)
constexpr int BSQ = NP / 4;          // 260 u64 per exchanged alpha row
constexpr int LQ = 274;              // u64 LDS row stride (bank-clean b128 reads)
constexpr int TOTQ = MB * BSQ;       // 4160 u64 per batch-block alpha
constexpr int NLD = TOTQ / CBLK;     // 13 loads per thread, EXACT (no remainder)
constexpr u64 SMASK = 0x7FFF7FFF7FFF7FFFull;

__device__ __forceinline__ unsigned short f2bf(float f) {
  union { float f; unsigned u; } v; v.f = f;
  return (unsigned short)((v.u + 0x7fffu + ((v.u >> 16) & 1u)) >> 16);
}

__device__ __forceinline__ u64 ald8(const u64* p) {
  return __hip_atomic_load((u64*)p, __ATOMIC_RELAXED, __HIP_MEMORY_SCOPE_AGENT);
}
__device__ __forceinline__ void ast8(u64* p, u64 v) {
  __hip_atomic_store(p, v, __ATOMIC_RELAXED, __HIP_MEMORY_SCOPE_AGENT);
}

// Poll an alpha word until its parity bit (bit 15 of every half, set by the
// producer's single atomic 8B store) matches par. Returns the raw word.
__device__ __forceinline__ u64 poll_word(const u64* p, unsigned par, u64 first) {
  u64 v = first;
  while ((unsigned)((v >> 15) & 1ull) != par) {
    __builtin_amdgcn_s_sleep(1);
    v = ald8(p);
  }
  return v;
}

__device__ __forceinline__ float sum4bf(u64 q) {
  union { unsigned u; float f; } a, b, c, d;
  a.u = ((unsigned)(q & 0xFFFFu)) << 16;
  b.u = ((unsigned)((q >> 16) & 0xFFFFu)) << 16;
  c.u = ((unsigned)((q >> 32) & 0xFFFFu)) << 16;
  d.u = ((unsigned)((q >> 48) & 0xFFFFu)) << 16;
  return (a.f + b.f) + (c.f + d.f);
}

__global__ void k_zero(u32x4* p, int n) {
  int i = blockIdx.x * blockDim.x + threadIdx.x;
  if (i < n) p[i] = (u32x4){0u, 0u, 0u, 0u};
}

// Poison: sign bits set (parity 1) so slot-2's pre-first-write content reads
// as "not arrived" at t=3 (expected parity 0).
__global__ void k_fill(u32x4* p, int n) {
  int i = blockIdx.x * blockDim.x + threadIdx.x;
  if (i < n) p[i] = (u32x4){0x80008000u, 0x80008000u, 0x80008000u, 0x80008000u};
}

__global__ void k_prep_init(const float* __restrict__ il, float* __restrict__ ip) {
  __shared__ float red[1024];
  int tid = threadIdx.x;
  float m = -1e30f;
  for (int q = tid; q < QQ; q += 1024) m = fmaxf(m, il[q]);
  red[tid] = m; __syncthreads();
  for (int off = 512; off > 0; off >>= 1) {
    if (tid < off) red[tid] = fmaxf(red[tid], red[tid + off]);
    __syncthreads();
  }
  m = red[0]; __syncthreads();
  float s = 0.f;
  for (int q = tid; q < QQ; q += 1024) s += expf(il[q] - m);
  red[tid] = s; __syncthreads();
  for (int off = 512; off > 0; off >>= 1) {
    if (tid < off) red[tid] += red[tid + off];
    __syncthreads();
  }
  s = red[0];
  float inv = 1.0f / s;
  for (int q = tid; q < QQ; q += 1024) ip[q] = expf(il[q] - m) * inv;
}

__global__ void k_prep_B(const float* __restrict__ bl, float* __restrict__ bt) {
  int q = blockIdx.x * blockDim.x + threadIdx.x;
  if (q >= QQ) return;
  const float* row = bl + (size_t)q * SS;
  float m = -1e30f;
  for (int c = 0; c < SS; ++c) m = fmaxf(m, row[c]);
  float s = 0.f;
  for (int c = 0; c < SS; ++c) s += expf(row[c] - m);
  float inv = 1.0f / s;
  for (int c = 0; c < SS; ++c) bt[c * BTS + q] = expf(row[c] - m) * inv;
}

// Row r of A -> column r of A^T[n][k] (bf16), K-stride KP (pads stay zero)
__global__ void k_prep_A(const float* __restrict__ al, unsigned short* __restrict__ at) {
  int r = blockIdx.x;
  const float* row = al + (size_t)r * QQ;
  __shared__ float red[256];
  int tid = threadIdx.x;
  float m = -1e30f;
  for (int n = tid; n < QQ; n += 256) m = fmaxf(m, row[n]);
  red[tid] = m; __syncthreads();
  for (int off = 128; off > 0; off >>= 1) {
    if (tid < off) red[tid] = fmaxf(red[tid], red[tid + off]);
    __syncthreads();
  }
  m = red[0]; __syncthreads();
  float s = 0.f;
  for (int n = tid; n < QQ; n += 256) s += expf(row[n] - m);
  red[tid] = s; __syncthreads();
  for (int off = 128; off > 0; off >>= 1) {
    if (tid < off) red[tid] += red[tid + off];
    __syncthreads();
  }
  s = red[0];
  float inv = 1.0f / s;
  for (int n = tid; n < QQ; n += 256) at[(size_t)n * KP + r] = f2bf(expf(row[n] - m) * inv);
}

// f0 = init * E[:,0] into slot 0 (sign bits 0 = parity(t=0)); rows are NP long.
__global__ void k_init_step(const int* __restrict__ seq, const float* __restrict__ ip,
                            const float* __restrict__ Bt, unsigned short* __restrict__ buf0) {
  int b = blockIdx.x, tid = threadIdx.x;
  int c0 = seq[b * TT];
  for (int q = tid; q < NP; q += 256)
    buf0[(size_t)b * NP + q] = f2bf(ip[q] * Bt[c0 * BTS + q]);
}

__global__ __launch_bounds__(CBLK, 1) void k_hmm_coop(
    const int* __restrict__ seq, const unsigned short* __restrict__ At,
    const float* __restrict__ Bt, unsigned short* __restrict__ bufB,
    float* __restrict__ out) {
  __shared__ u64 aldsq[MB * LQ];          // ~35 KB: this block's alpha (bf16)
  __shared__ float srowF[MB];             // final-step row sums only

  const int tid = threadIdx.x, wg = blockIdx.x;
  const int bb = wg % NBB, sl = wg / NBB; // 13 slice-WGs per batch block
  const int lane = tid & 63, wv = tid >> 6;
  const int lrow = lane >> 4, lcol = lane & 15;
  const int n0w = (sl * NWV + wv) * 16;   // this wave's 16-col tile base

  // LDS K-pad (u64 cols 260..263 of each row): zero once, never rewritten
  if (tid < 64) aldsq[(tid >> 2) * LQ + 260 + (tid & 3)] = 0;

  // step-invariant At fragments
  u32x4 atr[KSTEPS];
  {
    const u32x4* atp = (const u32x4*)(At + (size_t)(n0w + lcol) * KP + 8 * lrow);
#pragma unroll
    for (int ks = 0; ks < KSTEPS; ++ks) atr[ks] = atp[4 * ks];
  }
  const u32x4 ones4 = (u32x4){0x3F803F80u, 0x3F803F80u, 0x3F803F80u, 0x3F803F80u};

  float ll = 0.f;

  for (int t = 1; t < TT; ++t) {
    const int rd = (t - 1) % 3, wri = t % 3;
    const unsigned par = (unsigned)((t - 1) & 1);   // expected parity of inputs
    const u64 wtag = (u64)(unsigned)(t & 1) << 15;  // sign bit for our outputs
    const u64* ain = (const u64*)(bufB + (size_t)rd * BUFN) + (size_t)bb * TOTQ;
    u64* wbuf8 = (u64*)(bufB + (size_t)wri * BUFN);

    // off-critical-path: emission quad (L2-resident, no exchange dependency)
    const int ch = seq[(bb * MB + lcol) * TT + t];
    const f32x4 ev = *(const f32x4*)(Bt + (size_t)ch * BTS + n0w + 4 * lrow);

    // --- self-tagged alpha loads: issue all 13 with full MLP, then verify
    u64 av[NLD];
    const u64* asrc = ain + tid;
#pragma unroll
    for (int j = 0; j < NLD; ++j) av[j] = ald8(asrc + j * CBLK);
#pragma unroll
    for (int j = 0; j < NLD; ++j)
      av[j] = poll_word(asrc + j * CBLK, par, av[j]) & SMASK;

    // --- stage into LDS (row stride LQ; only cols <260 written)
#pragma unroll
    for (int j = 0; j < NLD; ++j) {
      int g = tid + j * CBLK;
      int r = g / BSQ;
      aldsq[r * LQ + (g - r * BSQ)] = av[j];
    }
    __syncthreads();  // LDS alpha ready

    // --- k-loop: each ds_read feeds the GEMM MFMA and the ones-row-sum MFMA
    const u32x4* ap = ((const u32x4*)aldsq) + lcol * (LQ / 2) + lrow;
    f32x4 acc = (f32x4){0.f, 0.f, 0.f, 0.f};
    f32x4 accs = (f32x4){0.f, 0.f, 0.f, 0.f};
#pragma unroll
    for (int ks = 0; ks < KSTEPS; ++ks) {
      u32x4 af = ap[4 * ks];
      acc = __builtin_amdgcn_mfma_f32_16x16x32_bf16(
          __builtin_bit_cast(bf16x8, atr[ks]), __builtin_bit_cast(bf16x8, af),
          acc, 0, 0, 0);
      accs = __builtin_amdgcn_mfma_f32_16x16x32_bf16(
          __builtin_bit_cast(bf16x8, ones4), __builtin_bit_cast(bf16x8, af),
          accs, 0, 0, 0);
    }

    // --- epilogue: s in-register; store self-tagged alpha word; NO drain/tag
    const float s = accs[0];              // = sum_k f[lcol][k]
    const float inv = 1.0f / s;
    if (sl == 0 && wv == 0) ll += logf(s);

    u64 hv = 0;
#pragma unroll
    for (int i = 0; i < 4; ++i) {
      float v = acc[i] * ev[i] * inv;     // v >= 0, sign bit clear
      hv |= ((u64)f2bf(v) | wtag) << (16 * i);
    }
    ast8(wbuf8 + (size_t)(bb * MB + lcol) * BSQ + (n0w >> 2) + lrow, hv);
    __syncthreads();  // re-align waves before aldsq reuse next step
  }

  // --- final: sl==0 WGs sum alpha_{T-1} (parity (TT-1)&1) and write out
  if (sl == 0) {
    if (tid < MB) srowF[tid] = 0.f;
    __syncthreads();
    const int fs = (TT - 1) % 3;
    const unsigned parF = (unsigned)((TT - 1) & 1);
    const u64* ain = (const u64*)(bufB + (size_t)fs * BUFN) + (size_t)bb * TOTQ;
#pragma unroll
    for (int j = 0; j < NLD; ++j) {
      int g = tid + j * CBLK;
      u64 q = poll_word(ain + g, parF, ald8(ain + g)) & SMASK;
      atomicAdd(&srowF[g / BSQ], sum4bf(q));
    }
    __syncthreads();
    if (wv == 0 && lrow == 0) out[bb * MB + lcol] = ll + logf(srowF[lcol]);
  }
}

extern "C" void kernel_launch(void* const* d_in, const int* in_sizes, int n_in,
                              void* d_out, int out_size, void* d_ws, size_t ws_size,
                              hipStream_t stream) {
  const int* seq = (const int*)d_in[0];
  const float* Al = (const float*)d_in[1];
  const float* Bl = (const float*)d_in[2];
  const float* il = (const float*)d_in[3];
  float* out = (float*)d_out;

  char* ws = (char*)d_ws;
  unsigned short* At = (unsigned short*)ws;               // 1040*1056*2 = 2,196,480
  size_t off_bt = (size_t)NP * KP * 2;
  float* Bt = (float*)(ws + off_bt);                      // 26*1040*4 = 108,160
  size_t off_ip = off_bt + (size_t)SS * BTS * 4;
  float* ip = (float*)(ws + off_ip);                      // 1040*4
  size_t off_buf = off_ip + (size_t)NP * 4;
  unsigned short* bufB = (unsigned short*)(ws + off_buf); // 3*256*1040*2 = 1,597,440
  size_t total = off_buf + (size_t)3 * BUFN * 2;
  int n16 = (int)((total + 15) / 16);

  k_zero<<<(n16 + 255) / 256, 256, 0, stream>>>((u32x4*)ws, n16);
  // poison slot 2 so its pre-first-write content reads as "not arrived" at t=3
  int nf = (int)(((size_t)BUFN * 2) / 16);
  k_fill<<<(nf + 255) / 256, 256, 0, stream>>>(
      (u32x4*)(bufB + (size_t)2 * BUFN), nf);
  k_prep_init<<<1, 1024, 0, stream>>>(il, ip);
  k_prep_B<<<(QQ + 255) / 256, 256, 0, stream>>>(Bl, Bt);
  k_prep_A<<<QQ, 256, 0, stream>>>(Al, At);
  k_init_step<<<NB, 256, 0, stream>>>(seq, ip, Bt, bufB);

  void* args[] = {(void*)&seq, (void*)&At, (void*)&Bt, (void*)&bufB, (void*)&out};
  hipLaunchCooperativeKernel((void*)k_hmm_coop, dim3(NBB * NSL), dim3(CBLK),
                             args, 0, stream);
}

// Round 13
// 1562.385 us; speedup vs baseline: 1.2327x; 1.2327x over previous
//
#include <hip/hip_runtime.h>
#include <math.h>

typedef __bf16 bf16x8 __attribute__((ext_vector_type(8)));
typedef float f32x4 __attribute__((ext_vector_type(4)));
typedef unsigned int u32x4 __attribute__((ext_vector_type(4)));
typedef unsigned long long u64;

constexpr int QQ = 1027;   // states
constexpr int SS = 26;     // alphabet
constexpr int TT = 512;    // sequence length
constexpr int NB = 256;    // batch
constexpr int KP = 1056;   // K padded in LDS (33 ksteps of 32)
constexpr int NP = 1040;   // N padded (65 tiles of 16) = exchanged row length
constexpr int BTS = 1040;  // Bt row stride (floats)
constexpr int NSL = 13;    // N slices (5 tiles = 80 cols each)
constexpr int NBB = 16;    // batch blocks
constexpr int MB = 16;     // batch rows per block
constexpr int NWV = 5;     // waves per WG (1 col-tile each)
constexpr int CBLK = NWV * 64;       // 320
constexpr int KSTEPS = KP / 32;      // 33
constexpr int BUFN = NB * NP;        // bf16 elems per alpha slot (no pads)
constexpr int BSQ = NP / 4;          // 260 u64 per exchanged alpha row
constexpr int LQ = 274;              // u64 LDS row stride (bank-clean b128 reads)
constexpr int TOTQ = MB * BSQ;       // 4160 u64 per batch-block alpha
constexpr int NLD = TOTQ / CBLK;     // 13 loads per thread, EXACT
constexpr u64 SMASK = 0x7FFF7FFF7FFF7FFFull;

__device__ __forceinline__ unsigned short f2bf(float f) {
  union { float f; unsigned u; } v; v.f = f;
  return (unsigned short)((v.u + 0x7fffu + ((v.u >> 16) & 1u)) >> 16);
}

__device__ __forceinline__ u64 ald8(const u64* p) {
  return __hip_atomic_load((u64*)p, __ATOMIC_RELAXED, __HIP_MEMORY_SCOPE_AGENT);
}
__device__ __forceinline__ void ast8(u64* p, u64 v) {
  __hip_atomic_store(p, v, __ATOMIC_RELAXED, __HIP_MEMORY_SCOPE_AGENT);
}

__device__ __forceinline__ float sum4bf(u64 q) {
  union { unsigned u; float f; } a, b, c, d;
  a.u = ((unsigned)(q & 0xFFFFu)) << 16;
  b.u = ((unsigned)((q >> 16) & 0xFFFFu)) << 16;
  c.u = ((unsigned)((q >> 32) & 0xFFFFu)) << 16;
  d.u = ((unsigned)((q >> 48) & 0xFFFFu)) << 16;
  return (a.f + b.f) + (c.f + d.f);
}

__global__ void k_zero(u32x4* p, int n) {
  int i = blockIdx.x * blockDim.x + threadIdx.x;
  if (i < n) p[i] = (u32x4){0u, 0u, 0u, 0u};
}

// Poison: sign bits set (parity 1) so slot-2's pre-first-write content reads
// as "not arrived" at t=3 (expected parity 0).
__global__ void k_fill(u32x4* p, int n) {
  int i = blockIdx.x * blockDim.x + threadIdx.x;
  if (i < n) p[i] = (u32x4){0x80008000u, 0x80008000u, 0x80008000u, 0x80008000u};
}

__global__ void k_prep_init(const float* __restrict__ il, float* __restrict__ ip) {
  __shared__ float red[1024];
  int tid = threadIdx.x;
  float m = -1e30f;
  for (int q = tid; q < QQ; q += 1024) m = fmaxf(m, il[q]);
  red[tid] = m; __syncthreads();
  for (int off = 512; off > 0; off >>= 1) {
    if (tid < off) red[tid] = fmaxf(red[tid], red[tid + off]);
    __syncthreads();
  }
  m = red[0]; __syncthreads();
  float s = 0.f;
  for (int q = tid; q < QQ; q += 1024) s += expf(il[q] - m);
  red[tid] = s; __syncthreads();
  for (int off = 512; off > 0; off >>= 1) {
    if (tid < off) red[tid] += red[tid + off];
    __syncthreads();
  }
  s = red[0];
  float inv = 1.0f / s;
  for (int q = tid; q < QQ; q += 1024) ip[q] = expf(il[q] - m) * inv;
}

__global__ void k_prep_B(const float* __restrict__ bl, float* __restrict__ bt) {
  int q = blockIdx.x * blockDim.x + threadIdx.x;
  if (q >= QQ) return;
  const float* row = bl + (size_t)q * SS;
  float m = -1e30f;
  for (int c = 0; c < SS; ++c) m = fmaxf(m, row[c]);
  float s = 0.f;
  for (int c = 0; c < SS; ++c) s += expf(row[c] - m);
  float inv = 1.0f / s;
  for (int c = 0; c < SS; ++c) bt[c * BTS + q] = expf(row[c] - m) * inv;
}

// Row r of A -> column r of A^T[n][k] (bf16), K-stride KP (pads stay zero)
__global__ void k_prep_A(const float* __restrict__ al, unsigned short* __restrict__ at) {
  int r = blockIdx.x;
  const float* row = al + (size_t)r * QQ;
  __shared__ float red[256];
  int tid = threadIdx.x;
  float m = -1e30f;
  for (int n = tid; n < QQ; n += 256) m = fmaxf(m, row[n]);
  red[tid] = m; __syncthreads();
  for (int off = 128; off > 0; off >>= 1) {
    if (tid < off) red[tid] = fmaxf(red[tid], red[tid + off]);
    __syncthreads();
  }
  m = red[0]; __syncthreads();
  float s = 0.f;
  for (int n = tid; n < QQ; n += 256) s += expf(row[n] - m);
  red[tid] = s; __syncthreads();
  for (int off = 128; off > 0; off >>= 1) {
    if (tid < off) red[tid] += red[tid + off];
    __syncthreads();
  }
  s = red[0];
  float inv = 1.0f / s;
  for (int n = tid; n < QQ; n += 256) at[(size_t)n * KP + r] = f2bf(expf(row[n] - m) * inv);
}

// f0 = init * E[:,0] into slot 0 (sign bits 0 = parity(t=0)); rows are NP long.
__global__ void k_init_step(const int* __restrict__ seq, const float* __restrict__ ip,
                            const float* __restrict__ Bt, unsigned short* __restrict__ buf0) {
  int b = blockIdx.x, tid = threadIdx.x;
  int c0 = seq[b * TT];
  for (int q = tid; q < NP; q += 256)
    buf0[(size_t)b * NP + q] = f2bf(ip[q] * Bt[c0 * BTS + q]);
}

__global__ __launch_bounds__(CBLK, 1) void k_hmm_coop(
    const int* __restrict__ seq, const unsigned short* __restrict__ At,
    const float* __restrict__ Bt, unsigned short* __restrict__ bufB,
    float* __restrict__ out) {
  __shared__ u64 aldsq[MB * LQ];          // ~35 KB: this block's alpha (bf16)
  __shared__ float srowF[MB];             // final-step row sums only

  const int tid = threadIdx.x, wg = blockIdx.x;
  const int bb = wg % NBB, sl = wg / NBB; // 13 slice-WGs per batch block
  const int lane = tid & 63, wv = tid >> 6;
  const int lrow = lane >> 4, lcol = lane & 15;
  const int n0w = (sl * NWV + wv) * 16;   // this wave's 16-col tile base

  // LDS K-pad (u64 cols 260..263 of each row): zero once, never rewritten
  if (tid < 64) aldsq[(tid >> 2) * LQ + 260 + (tid & 3)] = 0;

  // step-invariant At fragments
  u32x4 atr[KSTEPS];
  {
    const u32x4* atp = (const u32x4*)(At + (size_t)(n0w + lcol) * KP + 8 * lrow);
#pragma unroll
    for (int ks = 0; ks < KSTEPS; ++ks) atr[ks] = atp[4 * ks];
  }
  const u32x4 ones4 = (u32x4){0x3F803F80u, 0x3F803F80u, 0x3F803F80u, 0x3F803F80u};

  float ll = 0.f;

  for (int t = 1; t < TT; ++t) {
    const int rd = (t - 1) % 3, wri = t % 3;
    const unsigned par = (unsigned)((t - 1) & 1);   // expected parity of inputs
    const u64 wtag = (u64)(unsigned)(t & 1) << 15;  // sign bit for our outputs
    const u64* ain = (const u64*)(bufB + (size_t)rd * BUFN) + (size_t)bb * TOTQ;
    u64* wbuf8 = (u64*)(bufB + (size_t)wri * BUFN);

    // off-critical-path: emission quad (L2-resident, no exchange dependency)
    const int ch = seq[(bb * MB + lcol) * TT + t];
    const f32x4 ev = *(const f32x4*)(Bt + (size_t)ch * BTS + n0w + 4 * lrow);

    // --- self-tagged alpha loads: issue all 13 (full MLP), then ROUND-parallel
    // re-poll: each retry round re-issues ALL pending loads back-to-back, so
    // the cost per round is ~1 L3 RT regardless of how many words are stale.
    u64 av[NLD];
    const u64* asrc = ain + tid;
#pragma unroll
    for (int j = 0; j < NLD; ++j) av[j] = ald8(asrc + j * CBLK);
    unsigned pend = (1u << NLD) - 1;
    while (true) {
      unsigned np = 0;
#pragma unroll
      for (int j = 0; j < NLD; ++j)
        if ((pend >> j) & 1u)
          if ((unsigned)((av[j] >> 15) & 1ull) != par) np |= 1u << j;
      pend = np;
      if (!pend) break;
      __builtin_amdgcn_s_sleep(1);
#pragma unroll
      for (int j = 0; j < NLD; ++j)
        if ((pend >> j) & 1u) av[j] = ald8(asrc + j * CBLK);
    }
#pragma unroll
    for (int j = 0; j < NLD; ++j) av[j] &= SMASK;

    // --- stage into LDS (row stride LQ; only cols <260 written)
#pragma unroll
    for (int j = 0; j < NLD; ++j) {
      int g = tid + j * CBLK;
      int r = g / BSQ;
      aldsq[r * LQ + (g - r * BSQ)] = av[j];
    }
    __syncthreads();  // LDS alpha ready

    // --- k-loop: each ds_read feeds the GEMM MFMA and the ones-row-sum MFMA
    const u32x4* ap = ((const u32x4*)aldsq) + lcol * (LQ / 2) + lrow;
    f32x4 acc = (f32x4){0.f, 0.f, 0.f, 0.f};
    f32x4 accs = (f32x4){0.f, 0.f, 0.f, 0.f};
#pragma unroll
    for (int ks = 0; ks < KSTEPS; ++ks) {
      u32x4 af = ap[4 * ks];
      acc = __builtin_amdgcn_mfma_f32_16x16x32_bf16(
          __builtin_bit_cast(bf16x8, atr[ks]), __builtin_bit_cast(bf16x8, af),
          acc, 0, 0, 0);
      accs = __builtin_amdgcn_mfma_f32_16x16x32_bf16(
          __builtin_bit_cast(bf16x8, ones4), __builtin_bit_cast(bf16x8, af),
          accs, 0, 0, 0);
    }

    // --- epilogue: s in-register; store self-tagged alpha word; NO drain/tag
    const float s = accs[0];              // = sum_k f[lcol][k]
    const float inv = 1.0f / s;
    if (sl == 0 && wv == 0) ll += logf(s);

    u64 hv = 0;
#pragma unroll
    for (int i = 0; i < 4; ++i) {
      float v = acc[i] * ev[i] * inv;     // v >= 0, sign bit clear
      hv |= ((u64)f2bf(v) | wtag) << (16 * i);
    }
    ast8(wbuf8 + (size_t)(bb * MB + lcol) * BSQ + (n0w >> 2) + lrow, hv);
    __syncthreads();  // re-align waves before aldsq reuse next step
  }

  // --- final: sl==0 WGs sum alpha_{T-1} (parity (TT-1)&1) and write out
  if (sl == 0) {
    if (tid < MB) srowF[tid] = 0.f;
    __syncthreads();
    const int fs = (TT - 1) % 3;
    const unsigned parF = (unsigned)((TT - 1) & 1);
    const u64* ain = (const u64*)(bufB + (size_t)fs * BUFN) + (size_t)bb * TOTQ;
#pragma unroll
    for (int j = 0; j < NLD; ++j) {
      int g = tid + j * CBLK;
      u64 q = ald8(ain + g);
      while ((unsigned)((q >> 15) & 1ull) != parF) {
        __builtin_amdgcn_s_sleep(1);
        q = ald8(ain + g);
      }
      atomicAdd(&srowF[g / BSQ], sum4bf(q & SMASK));
    }
    __syncthreads();
    if (wv == 0 && lrow == 0) out[bb * MB + lcol] = ll + logf(srowF[lcol]);
  }
}

extern "C" void kernel_launch(void* const* d_in, const int* in_sizes, int n_in,
                              void* d_out, int out_size, void* d_ws, size_t ws_size,
                              hipStream_t stream) {
  const int* seq = (const int*)d_in[0];
  const float* Al = (const float*)d_in[1];
  const float* Bl = (const float*)d_in[2];
  const float* il = (const float*)d_in[3];
  float* out = (float*)d_out;

  char* ws = (char*)d_ws;
  unsigned short* At = (unsigned short*)ws;               // 1040*1056*2 = 2,196,480
  size_t off_bt = (size_t)NP * KP * 2;
  float* Bt = (float*)(ws + off_bt);                      // 26*1040*4 = 108,160
  size_t off_ip = off_bt + (size_t)SS * BTS * 4;
  float* ip = (float*)(ws + off_ip);                      // 1040*4
  size_t off_buf = off_ip + (size_t)NP * 4;
  unsigned short* bufB = (unsigned short*)(ws + off_buf); // 3*256*1040*2 = 1,597,440
  size_t total = off_buf + (size_t)3 * BUFN * 2;
  int n16 = (int)((total + 15) / 16);

  k_zero<<<(n16 + 255) / 256, 256, 0, stream>>>((u32x4*)ws, n16);
  // poison slot 2 so its pre-first-write content reads as "not arrived" at t=3
  int nf = (int)(((size_t)BUFN * 2) / 16);
  k_fill<<<(nf + 255) / 256, 256, 0, stream>>>(
      (u32x4*)(bufB + (size_t)2 * BUFN), nf);
  k_prep_init<<<1, 1024, 0, stream>>>(il, ip);
  k_prep_B<<<(QQ + 255) / 256, 256, 0, stream>>>(Bl, Bt);
  k_prep_A<<<QQ, 256, 0, stream>>>(Al, At);
  k_init_step<<<NB, 256, 0, stream>>>(seq, ip, Bt, bufB);

  void* args[] = {(void*)&seq, (void*)&At, (void*)&Bt, (void*)&bufB, (void*)&out};
  hipLaunchCooperativeKernel((void*)k_hmm_coop, dim3(NBB * NSL), dim3(CBLK),
                             args, 0, stream);
}